// Round 1
// baseline (254.554 us; speedup 1.0000x reference)
//
#include <hip/hip_runtime.h>

#define POOL 7

// One wave (64 lanes) per output point (box m, py, px); each lane handles 4
// channels via float4. 4 waves (4 points) per 256-thread block.
__global__ __launch_bounds__(256) void roialign_kernel(
    const float* __restrict__ boxes,       // [B*N, 4] (y1,x1,y2,x2) normalized
    const int*   __restrict__ image_shape, // [3]
    const float* __restrict__ feat2,       // [B,256,256,C]
    const float* __restrict__ feat3,       // [B,128,128,C]
    const float* __restrict__ feat4,       // [B, 64, 64,C]
    const float* __restrict__ feat5,       // [B, 32, 32,C]
    float*       __restrict__ out,         // [B*N, P, P, C]
    int B, int N, int C, int total_points)
{
    const int P = POOL;
    const int wave = threadIdx.x >> 6;          // 0..3
    const int lane = threadIdx.x & 63;          // 0..63
    const int pt   = blockIdx.x * 4 + wave;     // global point id
    if (pt >= total_points) return;

    const int m  = pt / (P * P);                // flat box index in [0, B*N)
    const int pp = pt - m * (P * P);
    const int py = pp / P;
    const int px = pp - py * P;
    const int b  = m / N;                       // batch index

    // --- box + level (wave-uniform scalar math) ---
    const float y1 = boxes[m * 4 + 0];
    const float x1 = boxes[m * 4 + 1];
    const float y2 = boxes[m * 4 + 2];
    const float x2 = boxes[m * 4 + 3];
    const float h  = y2 - y1;
    const float w  = x2 - x1;
    const float area = (float)(image_shape[0] * image_shape[1]);

    // lvl = clip(4 + round(log2(sqrt(w*h)*sqrt(area)/224)), 2, 5)
    const float lvlf = logf(sqrtf(w * h) * sqrtf(area) / 224.0f) * 1.4426950408889634f;
    const int lvl = (int)fminf(fmaxf(4.0f + rintf(lvlf), 2.0f), 5.0f);

    const float* feat;
    int H;
    switch (lvl) {
        case 2:  feat = feat2; H = 256; break;
        case 3:  feat = feat3; H = 128; break;
        case 4:  feat = feat4; H = 64;  break;
        default: feat = feat5; H = 32;  break;
    }
    const int W = H;

    // --- TF crop_and_resize sample coords ---
    const float sy = y1 * (float)(H - 1) + (float)py * (h * (float)(H - 1) / (float)(P - 1));
    const float sx = x1 * (float)(W - 1) + (float)px * (w * (float)(W - 1) / (float)(P - 1));

    const float y0f = floorf(sy);
    const float fy  = sy - y0f;
    int yi0 = (int)y0f;
    yi0 = yi0 < 0 ? 0 : (yi0 > H - 1 ? H - 1 : yi0);
    int yi1 = yi0 + 1 > H - 1 ? H - 1 : yi0 + 1;
    const bool vy = (sy >= 0.0f) && (sy <= (float)(H - 1));

    const float x0f = floorf(sx);
    const float fx  = sx - x0f;
    int xi0 = (int)x0f;
    xi0 = xi0 < 0 ? 0 : (xi0 > W - 1 ? W - 1 : xi0);
    int xi1 = xi0 + 1 > W - 1 ? W - 1 : xi0 + 1;
    const bool vx = (sx >= 0.0f) && (sx <= (float)(W - 1));

    const bool valid = vy && vx;

    // --- gather 4 corner rows, blend, store (lane -> 4 channels) ---
    const int c = lane * 4;                     // C == 256 -> 64 lanes * 4
    if (c >= C) return;

    const size_t planeB = (size_t)H * W * C;
    const float* fb = feat + (size_t)b * planeB;

    const size_t i00 = ((size_t)yi0 * W + xi0) * C + c;
    const size_t i01 = ((size_t)yi0 * W + xi1) * C + c;
    const size_t i10 = ((size_t)yi1 * W + xi0) * C + c;
    const size_t i11 = ((size_t)yi1 * W + xi1) * C + c;

    float4 r;
    if (valid) {
        const float4 v00 = *(const float4*)(fb + i00);
        const float4 v01 = *(const float4*)(fb + i01);
        const float4 v10 = *(const float4*)(fb + i10);
        const float4 v11 = *(const float4*)(fb + i11);

        const float gx = 1.0f - fx, gy = 1.0f - fy;
        r.x = (v00.x * gx + v01.x * fx) * gy + (v10.x * gx + v11.x * fx) * fy;
        r.y = (v00.y * gx + v01.y * fx) * gy + (v10.y * gx + v11.y * fx) * fy;
        r.z = (v00.z * gx + v01.z * fx) * gy + (v10.z * gx + v11.z * fx) * fy;
        r.w = (v00.w * gx + v01.w * fx) * gy + (v10.w * gx + v11.w * fx) * fy;
    } else {
        r.x = r.y = r.z = r.w = 0.0f;
    }

    *(float4*)(out + (size_t)pt * C + c) = r;
}

extern "C" void kernel_launch(void* const* d_in, const int* in_sizes, int n_in,
                              void* d_out, int out_size, void* d_ws, size_t ws_size,
                              hipStream_t stream) {
    const float* boxes       = (const float*)d_in[0];  // [B, N, 4]
    const int*   image_shape = (const int*)  d_in[1];  // [3]
    const float* feat2       = (const float*)d_in[2];  // [B,256,256,C]
    const float* feat3       = (const float*)d_in[3];
    const float* feat4       = (const float*)d_in[4];
    const float* feat5       = (const float*)d_in[5];
    float*       out         = (float*)d_out;

    const int B = 2;
    const int C = 256;
    const int N = in_sizes[0] / (B * 4);               // 1000
    const int total_points = B * N * POOL * POOL;      // 98000

    const int points_per_block = 4;                    // 4 waves/block
    const int grid = (total_points + points_per_block - 1) / points_per_block;

    roialign_kernel<<<grid, 256, 0, stream>>>(
        boxes, image_shape, feat2, feat3, feat4, feat5, out,
        B, N, C, total_points);
}